// Round 6
// baseline (687.020 us; speedup 1.0000x reference)
//
#include <hip/hip_runtime.h>
#include <hip/hip_bf16.h>

typedef unsigned int u32;
typedef unsigned short u16;
typedef unsigned long long u64;

// bf16 = top 16 bits of fp32; RNE pack
static __device__ __forceinline__ float bflo(u32 u) { return __uint_as_float(u << 16); }
static __device__ __forceinline__ float bfhi(u32 u) { return __uint_as_float(u & 0xFFFF0000u); }
static __device__ __forceinline__ float bf2f(u16 u) { return __uint_as_float((u32)u << 16); }
static __device__ __forceinline__ u32 f2bf(float f) {
    u32 u = __float_as_uint(f);
    return (u + 0x7FFFu + ((u >> 16) & 1u)) >> 16;
}
static __device__ __forceinline__ u32 packbf(float lo, float hi) {
    return f2bf(lo) | (f2bf(hi) << 16);
}
static __device__ __forceinline__ float ldf(const u16* p16, int idx, int isf32) {
    return isf32 ? ((const float*)p16)[idx] : bf2f(p16[idx]);
}
static __device__ __forceinline__ float sanitize(float v, float code) {
    return (fabsf(v) < 1e30f) ? v : code;
}

static __device__ __forceinline__ float wave_sum(float v) {
#pragma unroll
    for (int o = 32; o; o >>= 1) v += __shfl_xor(v, o, 64);
    return v;
}

// ---------------- diagnostics / utility ----------------

__global__ void k_sentinel(float* __restrict__ out, int n, float val) {
    int i = blockIdx.x * blockDim.x + threadIdx.x;
    if (i < n) out[i] = val;
}

__global__ void k_zero_sniff(int* __restrict__ p, int n, const u16* __restrict__ x,
                             int* __restrict__ flag) {
    int i = blockIdx.x * blockDim.x + threadIdx.x;
    if (i < n) p[i] = 0;
    if (blockIdx.x == 0 && threadIdx.x < 64) {
        int lane = threadIdx.x;
        int wild = 0;
        for (int k = 0; k < 64; k++) {
            u32 u = x[lane * 64 + k];
            int e = (u >> 7) & 0xFF;
            if (e < 96 || e > 135) wild++;
        }
        float tot = wave_sum((float)wild);
        if (lane == 0) *flag = (tot > 200.f) ? 1 : 0;
    }
}

// ---------------- sort-by-dst machinery ----------------

__global__ void k_hist(const int* __restrict__ dst, int E, int* __restrict__ deg) {
    int i = blockIdx.x * blockDim.x + threadIdx.x;
    if (i < E) atomicAdd(&deg[dst[i]], 1);
}

__global__ void k_scan_partial(const int* __restrict__ deg, int n, int* __restrict__ bsum) {
    int t = threadIdx.x;
    int base = blockIdx.x * 1024 + t * 4;
    int s = 0;
#pragma unroll
    for (int j = 0; j < 4; j++) {
        int idx = base + j;
        if (idx < n) s += deg[idx];
    }
    __shared__ int sh[256];
    sh[t] = s;
    __syncthreads();
    for (int d = 128; d; d >>= 1) {
        if (t < d) sh[t] += sh[t + d];
        __syncthreads();
    }
    if (t == 0) bsum[blockIdx.x] = sh[0];
}

__global__ void k_scan_bsum(const int* __restrict__ bsum, int nb, int* __restrict__ boff) {
    int t = threadIdx.x;  // 256 threads
    int v = (t < nb) ? bsum[t] : 0;
    __shared__ int sh[256];
    sh[t] = v;
    __syncthreads();
    for (int d = 1; d < 256; d <<= 1) {
        int u = (t >= d) ? sh[t - d] : 0;
        __syncthreads();
        sh[t] += u;
        __syncthreads();
    }
    if (t < nb) boff[t] = sh[t] - v;  // exclusive
}

__global__ void k_scan_final(const int* __restrict__ deg, int n, const int* __restrict__ boff,
                             int* __restrict__ offsets, int Etot) {
    int t = threadIdx.x;
    int base = blockIdx.x * 1024 + t * 4;
    int v[4];
    int s = 0;
#pragma unroll
    for (int j = 0; j < 4; j++) {
        int idx = base + j;
        v[j] = (idx < n) ? deg[idx] : 0;
        s += v[j];
    }
    __shared__ int sh[256];
    sh[t] = s;
    __syncthreads();
    for (int d = 1; d < 256; d <<= 1) {
        int u = (t >= d) ? sh[t - d] : 0;
        __syncthreads();
        sh[t] += u;
        __syncthreads();
    }
    int ex = sh[t] - s + boff[blockIdx.x];
#pragma unroll
    for (int j = 0; j < 4; j++) {
        int idx = base + j;
        if (idx < n) offsets[idx] = ex;
        ex += v[j];
    }
    if (blockIdx.x == 0 && t == 0) offsets[n] = Etot;
}

// scatter edges into dst-sorted order; one 8B payload: low=src|fake<<20, high=bf16 (vl,vh)
__global__ void k_scatter(const int* __restrict__ src, const int* __restrict__ dst,
                          const u16* __restrict__ avl, const u16* __restrict__ avh,
                          const int* __restrict__ lab, int E,
                          const int* __restrict__ offsets, int* __restrict__ cursor,
                          u64* __restrict__ epay, const int* __restrict__ flag) {
    int i = blockIdx.x * blockDim.x + threadIdx.x;
    if (i >= E) return;
    int isf32 = *flag;
    int d = dst[i];
    int pos = offsets[d] + atomicAdd(&cursor[d], 1);
    if ((unsigned)pos >= (unsigned)E) return;
    int s = src[i];
    int sl = lab[s], dl = lab[d];
    int fake = (sl < 0 || dl < 0) ? 2 : ((sl != dl) ? 1 : 0);
    u32 lo32 = (u32)(s | (fake << 20));
    u32 hi32 = isf32 ? packbf(((const float*)avl)[i], ((const float*)avh)[i])
                     : ((u32)avl[i] | ((u32)avh[i] << 16));
    epay[pos] = ((u64)hi32 << 32) | lo32;
}

// ---------------- phase A: x @ {W_low, W_high, W_mlp} ----------------
// stores to xwfp (float2 pairs) if non-null, else xwlh (packed bf16)

__launch_bounds__(256) __global__
void k_gemm(const u16* __restrict__ x, const u16* __restrict__ wl, const u16* __restrict__ wh,
            const u16* __restrict__ wm, int N, float2* __restrict__ xwfp,
            u32* __restrict__ xwlh, float* __restrict__ omlp, const int* __restrict__ flag) {
    int isf32 = *flag;
    __shared__ float WL[4096], WH[4096], WM[4096];
    for (int i = threadIdx.x; i < 4096; i += 256) {
        WL[i] = ldf(wl, i, isf32);
        WH[i] = ldf(wh, i, isf32);
        WM[i] = ldf(wm, i, isf32);
    }
    __syncthreads();
    int lane = threadIdx.x & 63;
    int wid = (blockIdx.x * 256 + threadIdx.x) >> 6;
    int nw = gridDim.x * 4;
    for (int r0 = wid * 8; r0 < N; r0 += nw * 8) {
        float xv[8];
#pragma unroll
        for (int j = 0; j < 8; j++) xv[j] = ldf(x, (r0 + j) * 64 + lane, isf32);
        float aL[8], aH[8], aM[8];
#pragma unroll
        for (int j = 0; j < 8; j++) { aL[j] = 0.f; aH[j] = 0.f; aM[j] = 0.f; }
        for (int k = 0; k < 64; k++) {
            float wlv = WL[k * 64 + lane];
            float whv = WH[k * 64 + lane];
            float wmv = WM[k * 64 + lane];
#pragma unroll
            for (int j = 0; j < 8; j++) {
                float xk = __shfl(xv[j], k, 64);
                aL[j] += xk * wlv;
                aH[j] += xk * whv;
                aM[j] += xk * wmv;
            }
        }
#pragma unroll
        for (int j = 0; j < 8; j++) {
            size_t o = (size_t)(r0 + j) * 64 + lane;
            float vl = sanitize(aL[j], 111.f), vh = sanitize(aH[j], 111.f);
            if (xwfp) xwfp[o] = make_float2(vl, vh);
            else xwlh[o] = packbf(vl, vh);
            omlp[o] = fmaxf(sanitize(aM[j], 111.f), 0.f);
        }
    }
}

// ---------------- phase B: spmm + relu (two storage tiers) ----------------

__launch_bounds__(256) __global__
void k_spmm_f32(const float2* __restrict__ xwfp, const u64* __restrict__ epay,
                const int* __restrict__ offsets, int N, float2* __restrict__ outfp) {
    int wid = __builtin_amdgcn_readfirstlane((blockIdx.x * blockDim.x + threadIdx.x) >> 6);
    int lane = threadIdx.x & 63;
    if (wid >= N) return;
    int s = offsets[wid], e = offsets[wid + 1];
    int Nm1 = N - 1;
    float al = 0.f, ah = 0.f;
    for (int j = s; j < e; j += 8) {
        float2 row[8];
        float vl[8], vh[8];
#pragma unroll
        for (int t = 0; t < 8; t++) {
            int idx = min(j + t, e - 1);             // clamped (branch-free tail)
            u64 p = epay[idx];                        // scalar 8B load
            int sj = min((int)(p & 0xFFFFF), Nm1);
            u32 v = (u32)(p >> 32);
            int valid = (j + t < e);
            vl[t] = valid ? bflo(v) : 0.f;            // zero-weight dup edges
            vh[t] = valid ? bfhi(v) : 0.f;
            row[t] = xwfp[(size_t)sj * 64 + lane];    // dwordx2 gather, 8 in flight
        }
#pragma unroll
        for (int t = 0; t < 8; t++) {
            al += vl[t] * row[t].x;
            ah += vh[t] * row[t].y;
        }
    }
    outfp[(size_t)wid * 64 + lane] = make_float2(fmaxf(al, 0.f), fmaxf(ah, 0.f));
}

__launch_bounds__(256) __global__
void k_spmm_bf(const u32* __restrict__ xwlh, const u64* __restrict__ epay,
               const int* __restrict__ offsets, int N, u32* __restrict__ outlh) {
    int wid = __builtin_amdgcn_readfirstlane((blockIdx.x * blockDim.x + threadIdx.x) >> 6);
    int lane = threadIdx.x & 63;
    if (wid >= N) return;
    int s = offsets[wid], e = offsets[wid + 1];
    int Nm1 = N - 1;
    float al = 0.f, ah = 0.f;
    for (int j = s; j < e; j += 8) {
        u32 row[8];
        float vl[8], vh[8];
#pragma unroll
        for (int t = 0; t < 8; t++) {
            int idx = min(j + t, e - 1);
            u64 p = epay[idx];
            int sj = min((int)(p & 0xFFFFF), Nm1);
            u32 v = (u32)(p >> 32);
            int valid = (j + t < e);
            vl[t] = valid ? bflo(v) : 0.f;
            vh[t] = valid ? bfhi(v) : 0.f;
            row[t] = xwlh[(size_t)sj * 64 + lane];
        }
#pragma unroll
        for (int t = 0; t < 8; t++) {
            al += vl[t] * bflo(row[t]);
            ah += vh[t] * bfhi(row[t]);
        }
    }
    outlh[(size_t)wid * 64 + lane] = packbf(fmaxf(al, 0.f), fmaxf(ah, 0.f));
}

// ---------------- phase C+D fused: masked aggregation + attention ----------------

static __device__ __forceinline__ void agg_epilogue(
    float hetL, float hetH, float homL, float homH, float unkL, float unkH,
    int wid, int lane, int isf32,
    const u16* aLF, const u16* aHF, const u16* aLB, const u16* aHB,
    const u16* aLU, const u16* aHU, const u16* aM, const u16* a7, float* out) {
    float mv = out[(size_t)wid * 64 + lane];  // omlp staged in d_out (f32)

    float d0 = wave_sum(hetL * ldf(aLF, lane, isf32));
    float d1 = wave_sum(hetH * ldf(aHF, lane, isf32));
    float d2 = wave_sum(homL * ldf(aLB, lane, isf32));
    float d3 = wave_sum(homH * ldf(aHB, lane, isf32));
    float d4 = wave_sum(unkL * ldf(aLU, lane, isf32));
    float d5 = wave_sum(unkH * ldf(aHU, lane, isf32));
    float d6 = wave_sum(mv * ldf(aM, lane, isf32));

    float f[7];
    f[0] = 1.f / (1.f + expf(-d0));
    f[1] = 1.f / (1.f + expf(-d1));
    f[2] = 1.f / (1.f + expf(-d2));
    f[3] = 1.f / (1.f + expf(-d3));
    f[4] = 1.f / (1.f + expf(-d4));
    f[5] = 1.f / (1.f + expf(-d5));
    f[6] = 1.f / (1.f + expf(-d6));

    float z[7];
#pragma unroll
    for (int jj = 0; jj < 7; jj++) {
        float acc = 0.f;
#pragma unroll
        for (int i = 0; i < 7; i++) acc += f[i] * ldf(a7, i * 7 + jj, isf32);
        z[jj] = acc * (1.f / 7.f);
    }
    float m = z[0];
#pragma unroll
    for (int jj = 1; jj < 7; jj++) m = fmaxf(m, z[jj]);
    float wsum = 0.f;
    float wv[7];
#pragma unroll
    for (int jj = 0; jj < 7; jj++) { wv[jj] = expf(z[jj] - m); wsum += wv[jj]; }

    float o = wv[0] * hetL + wv[1] * hetH + wv[2] * homL + wv[3] * homH + wv[4] * unkL +
              wv[5] * unkH + wv[6] * mv;
    o *= 7.f / wsum;
    out[(size_t)wid * 64 + lane] = sanitize(o, 333.f);
}

__launch_bounds__(256) __global__
void k_agg_f32(const float2* __restrict__ outfp, const u64* __restrict__ epay,
               const int* __restrict__ offsets,
               const u16* __restrict__ aLF, const u16* __restrict__ aHF,
               const u16* __restrict__ aLB, const u16* __restrict__ aHB,
               const u16* __restrict__ aLU, const u16* __restrict__ aHU,
               const u16* __restrict__ aM, const u16* __restrict__ a7, int N,
               float* __restrict__ out, const int* __restrict__ flag) {
    int isf32 = *flag;
    int wid = __builtin_amdgcn_readfirstlane((blockIdx.x * blockDim.x + threadIdx.x) >> 6);
    int lane = threadIdx.x & 63;
    if (wid >= N) return;
    int s = offsets[wid], e = offsets[wid + 1];
    int Nm1 = N - 1;
    float hetL = 0.f, hetH = 0.f, homL = 0.f, homH = 0.f, unkL = 0.f, unkH = 0.f;
    for (int j = s; j < e; j += 8) {
        float2 row[8];
        int fk[8];
        float wt[8];
#pragma unroll
        for (int t = 0; t < 8; t++) {
            int idx = min(j + t, e - 1);
            u64 p = epay[idx];
            int sj = min((int)(p & 0xFFFFF), Nm1);
            fk[t] = ((int)(p >> 20)) & 3;
            wt[t] = (j + t < e) ? 1.f : 0.f;
            row[t] = outfp[(size_t)sj * 64 + lane];
        }
#pragma unroll
        for (int t = 0; t < 8; t++) {
            if (fk[t] == 0) { homL += wt[t] * row[t].x; homH += wt[t] * row[t].y; }
            else if (fk[t] == 1) { hetL += wt[t] * row[t].x; hetH += wt[t] * row[t].y; }
            else { unkL += wt[t] * row[t].x; unkH += wt[t] * row[t].y; }
        }
    }
    agg_epilogue(hetL, hetH, homL, homH, unkL, unkH, wid, lane, isf32, aLF, aHF, aLB, aHB, aLU,
                 aHU, aM, a7, out);
}

__launch_bounds__(256) __global__
void k_agg_bf(const u32* __restrict__ outlh, const u64* __restrict__ epay,
              const int* __restrict__ offsets,
              const u16* __restrict__ aLF, const u16* __restrict__ aHF,
              const u16* __restrict__ aLB, const u16* __restrict__ aHB,
              const u16* __restrict__ aLU, const u16* __restrict__ aHU,
              const u16* __restrict__ aM, const u16* __restrict__ a7, int N,
              float* __restrict__ out, const int* __restrict__ flag) {
    int isf32 = *flag;
    int wid = __builtin_amdgcn_readfirstlane((blockIdx.x * blockDim.x + threadIdx.x) >> 6);
    int lane = threadIdx.x & 63;
    if (wid >= N) return;
    int s = offsets[wid], e = offsets[wid + 1];
    int Nm1 = N - 1;
    float hetL = 0.f, hetH = 0.f, homL = 0.f, homH = 0.f, unkL = 0.f, unkH = 0.f;
    for (int j = s; j < e; j += 8) {
        u32 row[8];
        int fk[8];
        float wt[8];
#pragma unroll
        for (int t = 0; t < 8; t++) {
            int idx = min(j + t, e - 1);
            u64 p = epay[idx];
            int sj = min((int)(p & 0xFFFFF), Nm1);
            fk[t] = ((int)(p >> 20)) & 3;
            wt[t] = (j + t < e) ? 1.f : 0.f;
            row[t] = outlh[(size_t)sj * 64 + lane];
        }
#pragma unroll
        for (int t = 0; t < 8; t++) {
            float lo = bflo(row[t]), hi = bfhi(row[t]);
            if (fk[t] == 0) { homL += wt[t] * lo; homH += wt[t] * hi; }
            else if (fk[t] == 1) { hetL += wt[t] * lo; hetH += wt[t] * hi; }
            else { unkL += wt[t] * lo; unkH += wt[t] * hi; }
        }
    }
    agg_epilogue(hetL, hetH, homL, homH, unkL, unkH, wid, lane, isf32, aLF, aHF, aLB, aHB, aLU,
                 aHU, aM, a7, out);
}

// ---------------- launcher ----------------

extern "C" void kernel_launch(void* const* d_in, const int* in_sizes, int n_in, void* d_out,
                              int out_size, void* d_ws, size_t ws_size, hipStream_t stream) {
    const u16* x = (const u16*)d_in[0];
    const u16* avl = (const u16*)d_in[1];
    const u16* avh = (const u16*)d_in[2];
    const u16* wl = (const u16*)d_in[3];
    const u16* wh = (const u16*)d_in[4];
    const u16* wm = (const u16*)d_in[5];
    const u16* aLF = (const u16*)d_in[6];
    const u16* aHF = (const u16*)d_in[7];
    const u16* aLB = (const u16*)d_in[8];
    const u16* aHB = (const u16*)d_in[9];
    const u16* aLU = (const u16*)d_in[10];
    const u16* aHU = (const u16*)d_in[11];
    const u16* aM = (const u16*)d_in[12];
    const u16* a7 = (const u16*)d_in[13];
    const int* esrc = (const int*)d_in[14];
    const int* edst = (const int*)d_in[15];
    const int* lab = (const int*)d_in[16];
    float* out = (float*)d_out;

    const int N = in_sizes[0] / 64;
    const int E = in_sizes[1];

    char* w = (char*)d_ws;
    size_t off = 0;
    auto alloc = [&](size_t bytes) -> char* {
        char* p = w + off;
        off += (bytes + 255) & ~(size_t)255;
        return p;
    };
    // common small arrays first
    int* flag = (int*)alloc(256);
    int* offsets = (int*)alloc((size_t)(N + 1) * 4);
    int* degcur = (int*)alloc((size_t)2 * N * 4);
    int* bsum = (int*)alloc(256 * 4);
    int* boff = (int*)alloc(256 * 4);
    u64* epay = (u64*)alloc((size_t)E * 8);
    size_t off_common = off;

    // tier A: f32-pair rows (needs ~116.5 MB)
    float2* xwfp = (float2*)alloc((size_t)N * 64 * 8);
    float2* outfp = (float2*)alloc((size_t)N * 64 * 8);
    size_t off_A = off;

    bool tierA = (ws_size >= off_A);
    u32* xwlh = nullptr;
    u32* outlh = nullptr;
    if (!tierA) {  // tier B: packed bf16 rows (~65 MB, proven to fit)
        off = off_common;
        xwlh = (u32*)alloc((size_t)N * 64 * 4);
        outlh = (u32*)alloc((size_t)N * 64 * 4);
        xwfp = nullptr;
        outfp = nullptr;
        if (ws_size < off) {
            k_sentinel<<<(out_size + 255) / 256, 256, 0, stream>>>(out, out_size, 1000.0f);
            return;
        }
    }

    int* deg = degcur;
    int* cursor = degcur + N;
    int NB = (N + 1023) / 1024;  // must be <= 256

    k_zero_sniff<<<(2 * N + 255) / 256, 256, 0, stream>>>(degcur, 2 * N, x, flag);
    k_hist<<<(E + 255) / 256, 256, 0, stream>>>(edst, E, deg);
    k_scan_partial<<<NB, 256, 0, stream>>>(deg, N, bsum);
    k_scan_bsum<<<1, 256, 0, stream>>>(bsum, NB, boff);
    k_scan_final<<<NB, 256, 0, stream>>>(deg, N, boff, offsets, E);
    k_scatter<<<(E + 255) / 256, 256, 0, stream>>>(esrc, edst, avl, avh, lab, E, offsets, cursor,
                                                   epay, flag);

    k_gemm<<<512, 256, 0, stream>>>(x, wl, wh, wm, N, xwfp, xwlh, out /* omlp in d_out */, flag);

    int nodeBlocks = (N * 64 + 255) / 256;
    if (tierA) {
        k_spmm_f32<<<nodeBlocks, 256, 0, stream>>>(xwfp, epay, offsets, N, outfp);
        k_agg_f32<<<nodeBlocks, 256, 0, stream>>>(outfp, epay, offsets, aLF, aHF, aLB, aHB, aLU,
                                                  aHU, aM, a7, N, out, flag);
    } else {
        k_spmm_bf<<<nodeBlocks, 256, 0, stream>>>(xwlh, epay, offsets, N, outlh);
        k_agg_bf<<<nodeBlocks, 256, 0, stream>>>(outlh, epay, offsets, aLF, aHF, aLB, aHB, aLU,
                                                 aHU, aM, a7, N, out, flag);
    }
}

// Round 7
// 611.464 us; speedup vs baseline: 1.1236x; 1.1236x over previous
//
#include <hip/hip_runtime.h>
#include <hip/hip_bf16.h>

typedef unsigned int u32;
typedef unsigned short u16;
typedef unsigned long long u64;

// bf16 = top 16 bits of fp32; RNE pack
static __device__ __forceinline__ float bflo(u32 u) { return __uint_as_float(u << 16); }
static __device__ __forceinline__ float bfhi(u32 u) { return __uint_as_float(u & 0xFFFF0000u); }
static __device__ __forceinline__ float bf2f(u16 u) { return __uint_as_float((u32)u << 16); }
static __device__ __forceinline__ u32 f2bf(float f) {
    u32 u = __float_as_uint(f);
    return (u + 0x7FFFu + ((u >> 16) & 1u)) >> 16;
}
static __device__ __forceinline__ u32 packbf(float lo, float hi) {
    return f2bf(lo) | (f2bf(hi) << 16);
}
static __device__ __forceinline__ float ldf(const u16* p16, int idx, int isf32) {
    return isf32 ? ((const float*)p16)[idx] : bf2f(p16[idx]);
}
// load 4 consecutive attention-vector elements [4*q .. 4*q+3]
static __device__ __forceinline__ void load4(const u16* p, int q, int isf32, float* v) {
    if (isf32) {
        float4 t = ((const float4*)p)[q];
        v[0] = t.x; v[1] = t.y; v[2] = t.z; v[3] = t.w;
    } else {
        u32 a = ((const u32*)p)[q * 2], b = ((const u32*)p)[q * 2 + 1];
        v[0] = bflo(a); v[1] = bfhi(a); v[2] = bflo(b); v[3] = bfhi(b);
    }
}
static __device__ __forceinline__ float sanitize(float v, float code) {
    return (fabsf(v) < 1e30f) ? v : code;
}

static __device__ __forceinline__ float wave_sum(float v) {
#pragma unroll
    for (int o = 32; o; o >>= 1) v += __shfl_xor(v, o, 64);
    return v;
}

// ---------------- diagnostics / utility ----------------

__global__ void k_sentinel(float* __restrict__ out, int n, float val) {
    int i = blockIdx.x * blockDim.x + threadIdx.x;
    if (i < n) out[i] = val;
}

__global__ void k_zero_sniff(int* __restrict__ p, int n, const u16* __restrict__ x,
                             int* __restrict__ flag) {
    int i = blockIdx.x * blockDim.x + threadIdx.x;
    if (i < n) p[i] = 0;
    if (blockIdx.x == 0 && threadIdx.x < 64) {
        int lane = threadIdx.x;
        int wild = 0;
        for (int k = 0; k < 64; k++) {
            u32 u = x[lane * 64 + k];
            int e = (u >> 7) & 0xFF;
            if (e < 96 || e > 135) wild++;
        }
        float tot = wave_sum((float)wild);
        if (lane == 0) *flag = (tot > 200.f) ? 1 : 0;
    }
}

// ---------------- sort-by-dst machinery ----------------

__global__ void k_hist(const int* __restrict__ dst, int E, int* __restrict__ deg) {
    int i = blockIdx.x * blockDim.x + threadIdx.x;
    if (i < E) atomicAdd(&deg[dst[i]], 1);
}

__global__ void k_scan_partial(const int* __restrict__ deg, int n, int* __restrict__ bsum) {
    int t = threadIdx.x;
    int base = blockIdx.x * 1024 + t * 4;
    int s = 0;
#pragma unroll
    for (int j = 0; j < 4; j++) {
        int idx = base + j;
        if (idx < n) s += deg[idx];
    }
    __shared__ int sh[256];
    sh[t] = s;
    __syncthreads();
    for (int d = 128; d; d >>= 1) {
        if (t < d) sh[t] += sh[t + d];
        __syncthreads();
    }
    if (t == 0) bsum[blockIdx.x] = sh[0];
}

__global__ void k_scan_bsum(const int* __restrict__ bsum, int nb, int* __restrict__ boff) {
    int t = threadIdx.x;  // 256 threads
    int v = (t < nb) ? bsum[t] : 0;
    __shared__ int sh[256];
    sh[t] = v;
    __syncthreads();
    for (int d = 1; d < 256; d <<= 1) {
        int u = (t >= d) ? sh[t - d] : 0;
        __syncthreads();
        sh[t] += u;
        __syncthreads();
    }
    if (t < nb) boff[t] = sh[t] - v;  // exclusive
}

__global__ void k_scan_final(const int* __restrict__ deg, int n, const int* __restrict__ boff,
                             int* __restrict__ offsets, int Etot) {
    int t = threadIdx.x;
    int base = blockIdx.x * 1024 + t * 4;
    int v[4];
    int s = 0;
#pragma unroll
    for (int j = 0; j < 4; j++) {
        int idx = base + j;
        v[j] = (idx < n) ? deg[idx] : 0;
        s += v[j];
    }
    __shared__ int sh[256];
    sh[t] = s;
    __syncthreads();
    for (int d = 1; d < 256; d <<= 1) {
        int u = (t >= d) ? sh[t - d] : 0;
        __syncthreads();
        sh[t] += u;
        __syncthreads();
    }
    int ex = sh[t] - s + boff[blockIdx.x];
#pragma unroll
    for (int j = 0; j < 4; j++) {
        int idx = base + j;
        if (idx < n) offsets[idx] = ex;
        ex += v[j];
    }
    if (blockIdx.x == 0 && t == 0) offsets[n] = Etot;
}

// scatter edges into dst-sorted order; one 8B payload: low=src|fake<<20, high=bf16 (vl,vh)
__global__ void k_scatter(const int* __restrict__ src, const int* __restrict__ dst,
                          const u16* __restrict__ avl, const u16* __restrict__ avh,
                          const int* __restrict__ lab, int E,
                          const int* __restrict__ offsets, int* __restrict__ cursor,
                          u64* __restrict__ epay, const int* __restrict__ flag) {
    int i = blockIdx.x * blockDim.x + threadIdx.x;
    if (i >= E) return;
    int isf32 = *flag;
    int d = dst[i];
    int pos = offsets[d] + atomicAdd(&cursor[d], 1);
    if ((unsigned)pos >= (unsigned)E) return;
    int s = src[i];
    int sl = lab[s], dl = lab[d];
    int fake = (sl < 0 || dl < 0) ? 2 : ((sl != dl) ? 1 : 0);
    u32 lo32 = (u32)(s | (fake << 20));
    u32 hi32 = isf32 ? packbf(((const float*)avl)[i], ((const float*)avh)[i])
                     : ((u32)avl[i] | ((u32)avh[i] << 16));
    epay[pos] = ((u64)hi32 << 32) | lo32;
}

// ---------------- phase A: x @ {W_low, W_high, W_mlp} ----------------

__launch_bounds__(256) __global__
void k_gemm(const u16* __restrict__ x, const u16* __restrict__ wl, const u16* __restrict__ wh,
            const u16* __restrict__ wm, int N, u32* __restrict__ xwlh, float* __restrict__ omlp,
            const int* __restrict__ flag) {
    int isf32 = *flag;
    __shared__ float WL[4096], WH[4096], WM[4096];
    for (int i = threadIdx.x; i < 4096; i += 256) {
        WL[i] = ldf(wl, i, isf32);
        WH[i] = ldf(wh, i, isf32);
        WM[i] = ldf(wm, i, isf32);
    }
    __syncthreads();
    int lane = threadIdx.x & 63;
    int wid = (blockIdx.x * 256 + threadIdx.x) >> 6;
    int nw = gridDim.x * 4;
    for (int r0 = wid * 8; r0 < N; r0 += nw * 8) {
        float xv[8];
#pragma unroll
        for (int j = 0; j < 8; j++) xv[j] = ldf(x, (r0 + j) * 64 + lane, isf32);
        float aL[8], aH[8], aM[8];
#pragma unroll
        for (int j = 0; j < 8; j++) { aL[j] = 0.f; aH[j] = 0.f; aM[j] = 0.f; }
        for (int k = 0; k < 64; k++) {
            float wlv = WL[k * 64 + lane];
            float whv = WH[k * 64 + lane];
            float wmv = WM[k * 64 + lane];
#pragma unroll
            for (int j = 0; j < 8; j++) {
                float xk = __shfl(xv[j], k, 64);
                aL[j] += xk * wlv;
                aH[j] += xk * whv;
                aM[j] += xk * wmv;
            }
        }
#pragma unroll
        for (int j = 0; j < 8; j++) {
            size_t o = (size_t)(r0 + j) * 64 + lane;
            xwlh[o] = packbf(sanitize(aL[j], 111.f), sanitize(aH[j], 111.f));
            omlp[o] = fmaxf(sanitize(aM[j], 111.f), 0.f);
        }
    }
}

// ---------------- phase B: spmm + relu, 4 edges per dwordx4 gather ----------------
// lane = (edge-slot e = lane>>4) x (feature-group g = lane&15, dwords 4g..4g+3)

__launch_bounds__(256) __global__
void k_spmm4(const u32* __restrict__ xwlh, const u64* __restrict__ epay,
             const int* __restrict__ offsets, int N, u32* __restrict__ outlh) {
    int wid = __builtin_amdgcn_readfirstlane((blockIdx.x * blockDim.x + threadIdx.x) >> 6);
    int lane = threadIdx.x & 63;
    if (wid >= N) return;
    int s = offsets[wid], e = offsets[wid + 1];
    int g = lane & 15, eslot = lane >> 4;
    int Nm1 = N - 1;
    float aL[4] = {0.f, 0.f, 0.f, 0.f}, aH[4] = {0.f, 0.f, 0.f, 0.f};
    for (int j = s; j < e; j += 8) {
        u64 p[8];
#pragma unroll
        for (int t = 0; t < 8; t++) p[t] = epay[min(j + t, e - 1)];  // scalar loads
#pragma unroll
        for (int h = 0; h < 2; h++) {
            int b = h * 4;
            u64 pe = (eslot & 2) ? ((eslot & 1) ? p[b + 3] : p[b + 2])
                                 : ((eslot & 1) ? p[b + 1] : p[b + 0]);
            int valid = (j + b + eslot < e);
            int sj = min((int)(pe & 0xFFFFF), Nm1);
            u32 vv = (u32)(pe >> 32);
            float vl = valid ? bflo(vv) : 0.f;  // tail: zero weight, dup row merges
            float vh = valid ? bfhi(vv) : 0.f;
            uint4 R = *((const uint4*)(xwlh + (size_t)sj * 64) + g);  // 4 rows / gather
            aL[0] += vl * bflo(R.x); aH[0] += vh * bfhi(R.x);
            aL[1] += vl * bflo(R.y); aH[1] += vh * bfhi(R.y);
            aL[2] += vl * bflo(R.z); aH[2] += vh * bfhi(R.z);
            aL[3] += vl * bflo(R.w); aH[3] += vh * bfhi(R.w);
        }
    }
    // reduce across the 4 edge-slots (lanes g, g+16, g+32, g+48)
#pragma unroll
    for (int k = 0; k < 4; k++) {
        aL[k] += __shfl_xor(aL[k], 16, 64);
        aL[k] += __shfl_xor(aL[k], 32, 64);
        aH[k] += __shfl_xor(aH[k], 16, 64);
        aH[k] += __shfl_xor(aH[k], 32, 64);
    }
    if (lane < 16) {
        uint4 W;
        W.x = packbf(fmaxf(aL[0], 0.f), fmaxf(aH[0], 0.f));
        W.y = packbf(fmaxf(aL[1], 0.f), fmaxf(aH[1], 0.f));
        W.z = packbf(fmaxf(aL[2], 0.f), fmaxf(aH[2], 0.f));
        W.w = packbf(fmaxf(aL[3], 0.f), fmaxf(aH[3], 0.f));
        ((uint4*)(outlh + (size_t)wid * 64))[g] = W;
    }
}

// ---------------- phase C+D fused: masked aggregation + attention ----------------

__launch_bounds__(256) __global__
void k_agg4(const u32* __restrict__ outlh, const u64* __restrict__ epay,
            const int* __restrict__ offsets,
            const u16* __restrict__ aLF, const u16* __restrict__ aHF,
            const u16* __restrict__ aLB, const u16* __restrict__ aHB,
            const u16* __restrict__ aLU, const u16* __restrict__ aHU,
            const u16* __restrict__ aM, const u16* __restrict__ a7, int N,
            float* __restrict__ out, const int* __restrict__ flag) {
    int isf32 = *flag;
    int wid = __builtin_amdgcn_readfirstlane((blockIdx.x * blockDim.x + threadIdx.x) >> 6);
    int lane = threadIdx.x & 63;
    if (wid >= N) return;
    int s = offsets[wid], e = offsets[wid + 1];
    int g = lane & 15, eslot = lane >> 4;
    int Nm1 = N - 1;
    float heL[4] = {0, 0, 0, 0}, heH[4] = {0, 0, 0, 0};
    float hoL[4] = {0, 0, 0, 0}, hoH[4] = {0, 0, 0, 0};
    float unL[4] = {0, 0, 0, 0}, unH[4] = {0, 0, 0, 0};
    for (int j = s; j < e; j += 8) {
        u64 p[8];
#pragma unroll
        for (int t = 0; t < 8; t++) p[t] = epay[min(j + t, e - 1)];
#pragma unroll
        for (int h = 0; h < 2; h++) {
            int b = h * 4;
            u64 pe = (eslot & 2) ? ((eslot & 1) ? p[b + 3] : p[b + 2])
                                 : ((eslot & 1) ? p[b + 1] : p[b + 0]);
            int valid = (j + b + eslot < e);
            int sj = min((int)(pe & 0xFFFFF), Nm1);
            int fk = (int)(pe >> 20) & 3;
            float whe = (valid && fk == 1) ? 1.f : 0.f;
            float who = (valid && fk == 0) ? 1.f : 0.f;
            float wun = (valid && fk == 2) ? 1.f : 0.f;
            uint4 R = *((const uint4*)(outlh + (size_t)sj * 64) + g);
            float lo0 = bflo(R.x), hi0 = bfhi(R.x);
            float lo1 = bflo(R.y), hi1 = bfhi(R.y);
            float lo2 = bflo(R.z), hi2 = bfhi(R.z);
            float lo3 = bflo(R.w), hi3 = bfhi(R.w);
            heL[0] += whe * lo0; heH[0] += whe * hi0;
            heL[1] += whe * lo1; heH[1] += whe * hi1;
            heL[2] += whe * lo2; heH[2] += whe * hi2;
            heL[3] += whe * lo3; heH[3] += whe * hi3;
            hoL[0] += who * lo0; hoH[0] += who * hi0;
            hoL[1] += who * lo1; hoH[1] += who * hi1;
            hoL[2] += who * lo2; hoH[2] += who * hi2;
            hoL[3] += who * lo3; hoH[3] += who * hi3;
            unL[0] += wun * lo0; unH[0] += wun * hi0;
            unL[1] += wun * lo1; unH[1] += wun * hi1;
            unL[2] += wun * lo2; unH[2] += wun * hi2;
            unL[3] += wun * lo3; unH[3] += wun * hi3;
        }
    }
    // attention-vector slices for this lane's 4 features
    float vLF[4], vHF[4], vLB[4], vHB[4], vLU[4], vHU[4], vM[4];
    load4(aLF, g, isf32, vLF);
    load4(aHF, g, isf32, vHF);
    load4(aLB, g, isf32, vLB);
    load4(aHB, g, isf32, vHB);
    load4(aLU, g, isf32, vLU);
    load4(aHU, g, isf32, vHU);
    load4(aM, g, isf32, vM);
    float4 MV = ((const float4*)(out + (size_t)wid * 64))[g];  // omlp staged in d_out
    float mvv[4] = {MV.x, MV.y, MV.z, MV.w};
    float msk = (lane < 16) ? 1.f : 0.f;  // mv replicated 4x across slots -> mask

    // 7 dot products: distributed partials sum linearly, no pre-reduction needed
    float p0 = 0, p1 = 0, p2 = 0, p3 = 0, p4 = 0, p5 = 0, p6 = 0;
#pragma unroll
    for (int k = 0; k < 4; k++) {
        p0 += heL[k] * vLF[k];
        p1 += heH[k] * vHF[k];
        p2 += hoL[k] * vLB[k];
        p3 += hoH[k] * vHB[k];
        p4 += unL[k] * vLU[k];
        p5 += unH[k] * vHU[k];
        p6 += mvv[k] * vM[k];
    }
    float d0 = wave_sum(p0), d1 = wave_sum(p1), d2 = wave_sum(p2), d3 = wave_sum(p3);
    float d4 = wave_sum(p4), d5 = wave_sum(p5), d6 = wave_sum(p6 * msk);

    float f[7];
    f[0] = 1.f / (1.f + expf(-d0));
    f[1] = 1.f / (1.f + expf(-d1));
    f[2] = 1.f / (1.f + expf(-d2));
    f[3] = 1.f / (1.f + expf(-d3));
    f[4] = 1.f / (1.f + expf(-d4));
    f[5] = 1.f / (1.f + expf(-d5));
    f[6] = 1.f / (1.f + expf(-d6));

    float z[7];
#pragma unroll
    for (int jj = 0; jj < 7; jj++) {
        float acc = 0.f;
#pragma unroll
        for (int i = 0; i < 7; i++) acc += f[i] * ldf(a7, i * 7 + jj, isf32);
        z[jj] = acc * (1.f / 7.f);
    }
    float m = z[0];
#pragma unroll
    for (int jj = 1; jj < 7; jj++) m = fmaxf(m, z[jj]);
    float wsum = 0.f;
    float wv[7];
#pragma unroll
    for (int jj = 0; jj < 7; jj++) { wv[jj] = expf(z[jj] - m); wsum += wv[jj]; }
    float s7 = 7.f / wsum;

    // per-feature combine, then reduce across edge-slots
    float o[4];
#pragma unroll
    for (int k = 0; k < 4; k++) {
        o[k] = wv[0] * heL[k] + wv[1] * heH[k] + wv[2] * hoL[k] + wv[3] * hoH[k] +
               wv[4] * unL[k] + wv[5] * unH[k];
        o[k] += __shfl_xor(o[k], 16, 64);
        o[k] += __shfl_xor(o[k], 32, 64);
    }
    if (lane < 16) {
        float4 W;
        W.x = sanitize((o[0] + wv[6] * mvv[0]) * s7, 333.f);
        W.y = sanitize((o[1] + wv[6] * mvv[1]) * s7, 333.f);
        W.z = sanitize((o[2] + wv[6] * mvv[2]) * s7, 333.f);
        W.w = sanitize((o[3] + wv[6] * mvv[3]) * s7, 333.f);
        ((float4*)(out + (size_t)wid * 64))[g] = W;
    }
}

// ---------------- launcher ----------------

extern "C" void kernel_launch(void* const* d_in, const int* in_sizes, int n_in, void* d_out,
                              int out_size, void* d_ws, size_t ws_size, hipStream_t stream) {
    const u16* x = (const u16*)d_in[0];
    const u16* avl = (const u16*)d_in[1];
    const u16* avh = (const u16*)d_in[2];
    const u16* wl = (const u16*)d_in[3];
    const u16* wh = (const u16*)d_in[4];
    const u16* wm = (const u16*)d_in[5];
    const u16* aLF = (const u16*)d_in[6];
    const u16* aHF = (const u16*)d_in[7];
    const u16* aLB = (const u16*)d_in[8];
    const u16* aHB = (const u16*)d_in[9];
    const u16* aLU = (const u16*)d_in[10];
    const u16* aHU = (const u16*)d_in[11];
    const u16* aM = (const u16*)d_in[12];
    const u16* a7 = (const u16*)d_in[13];
    const int* esrc = (const int*)d_in[14];
    const int* edst = (const int*)d_in[15];
    const int* lab = (const int*)d_in[16];
    float* out = (float*)d_out;

    const int N = in_sizes[0] / 64;
    const int E = in_sizes[1];

    char* w = (char*)d_ws;
    size_t off = 0;
    auto alloc = [&](size_t bytes) -> char* {
        char* p = w + off;
        off += (bytes + 255) & ~(size_t)255;
        return p;
    };
    int* flag = (int*)alloc(256);
    int* offsets = (int*)alloc((size_t)(N + 1) * 4);
    int* degcur = (int*)alloc((size_t)2 * N * 4);
    int* bsum = (int*)alloc(256 * 4);
    int* boff = (int*)alloc(256 * 4);
    u64* epay = (u64*)alloc((size_t)E * 8);
    u32* xwlh = (u32*)alloc((size_t)N * 64 * 4);
    u32* outlh = (u32*)alloc((size_t)N * 64 * 4);

    if (ws_size < off) {
        k_sentinel<<<(out_size + 255) / 256, 256, 0, stream>>>(out, out_size, 1000.0f);
        return;
    }

    int* deg = degcur;
    int* cursor = degcur + N;
    int NB = (N + 1023) / 1024;  // must be <= 256

    k_zero_sniff<<<(2 * N + 255) / 256, 256, 0, stream>>>(degcur, 2 * N, x, flag);
    k_hist<<<(E + 255) / 256, 256, 0, stream>>>(edst, E, deg);
    k_scan_partial<<<NB, 256, 0, stream>>>(deg, N, bsum);
    k_scan_bsum<<<1, 256, 0, stream>>>(bsum, NB, boff);
    k_scan_final<<<NB, 256, 0, stream>>>(deg, N, boff, offsets, E);
    k_scatter<<<(E + 255) / 256, 256, 0, stream>>>(esrc, edst, avl, avh, lab, E, offsets, cursor,
                                                   epay, flag);

    k_gemm<<<512, 256, 0, stream>>>(x, wl, wh, wm, N, xwlh, out /* omlp in d_out */, flag);

    int nodeBlocks = (N * 64 + 255) / 256;
    k_spmm4<<<nodeBlocks, 256, 0, stream>>>(xwlh, epay, offsets, N, outlh);
    k_agg4<<<nodeBlocks, 256, 0, stream>>>(outlh, epay, offsets, aLF, aHF, aLB, aHB, aLU, aHU, aM,
                                           a7, N, out, flag);
}

// Round 8
// 528.727 us; speedup vs baseline: 1.2994x; 1.1565x over previous
//
#include <hip/hip_runtime.h>
#include <hip/hip_bf16.h>

typedef unsigned int u32;
typedef unsigned short u16;
typedef unsigned long long u64;

// bf16 = top 16 bits of fp32; RNE pack
static __device__ __forceinline__ float bflo(u32 u) { return __uint_as_float(u << 16); }
static __device__ __forceinline__ float bfhi(u32 u) { return __uint_as_float(u & 0xFFFF0000u); }
static __device__ __forceinline__ float bf2f(u16 u) { return __uint_as_float((u32)u << 16); }
static __device__ __forceinline__ u32 f2bf(float f) {
    u32 u = __float_as_uint(f);
    return (u + 0x7FFFu + ((u >> 16) & 1u)) >> 16;
}
static __device__ __forceinline__ u32 packbf(float lo, float hi) {
    return f2bf(lo) | (f2bf(hi) << 16);
}
static __device__ __forceinline__ float ldf(const u16* p16, int idx, int isf32) {
    return isf32 ? ((const float*)p16)[idx] : bf2f(p16[idx]);
}
// load 4 consecutive attention-vector elements [4*q .. 4*q+3]
static __device__ __forceinline__ void load4(const u16* p, int q, int isf32, float* v) {
    if (isf32) {
        float4 t = ((const float4*)p)[q];
        v[0] = t.x; v[1] = t.y; v[2] = t.z; v[3] = t.w;
    } else {
        u32 a = ((const u32*)p)[q * 2], b = ((const u32*)p)[q * 2 + 1];
        v[0] = bflo(a); v[1] = bfhi(a); v[2] = bflo(b); v[3] = bfhi(b);
    }
}
static __device__ __forceinline__ float sanitize(float v, float code) {
    return (fabsf(v) < 1e30f) ? v : code;
}

static __device__ __forceinline__ float wave_sum(float v) {
#pragma unroll
    for (int o = 32; o; o >>= 1) v += __shfl_xor(v, o, 64);
    return v;
}
// sum within 16-lane group (lanes grouped by lane>>4)
static __device__ __forceinline__ float group_sum(float v) {
#pragma unroll
    for (int o = 8; o; o >>= 1) v += __shfl_xor(v, o, 64);
    return v;
}

// ---------------- diagnostics / utility ----------------

__global__ void k_sentinel(float* __restrict__ out, int n, float val) {
    int i = blockIdx.x * blockDim.x + threadIdx.x;
    if (i < n) out[i] = val;
}

__global__ void k_zero_sniff(int* __restrict__ p, int n, const u16* __restrict__ x,
                             int* __restrict__ flag) {
    int i = blockIdx.x * blockDim.x + threadIdx.x;
    if (i < n) p[i] = 0;
    if (blockIdx.x == 0 && threadIdx.x < 64) {
        int lane = threadIdx.x;
        int wild = 0;
        for (int k = 0; k < 64; k++) {
            u32 u = x[lane * 64 + k];
            int e = (u >> 7) & 0xFF;
            if (e < 96 || e > 135) wild++;
        }
        float tot = wave_sum((float)wild);
        if (lane == 0) *flag = (tot > 200.f) ? 1 : 0;
    }
}

// ---------------- sort-by-dst machinery ----------------

__global__ void k_hist(const int* __restrict__ dst, int E, int* __restrict__ deg) {
    int i = blockIdx.x * blockDim.x + threadIdx.x;
    if (i < E) atomicAdd(&deg[dst[i]], 1);
}

__global__ void k_scan_partial(const int* __restrict__ deg, int n, int* __restrict__ bsum) {
    int t = threadIdx.x;
    int base = blockIdx.x * 1024 + t * 4;
    int s = 0;
#pragma unroll
    for (int j = 0; j < 4; j++) {
        int idx = base + j;
        if (idx < n) s += deg[idx];
    }
    __shared__ int sh[256];
    sh[t] = s;
    __syncthreads();
    for (int d = 128; d; d >>= 1) {
        if (t < d) sh[t] += sh[t + d];
        __syncthreads();
    }
    if (t == 0) bsum[blockIdx.x] = sh[0];
}

__global__ void k_scan_bsum(const int* __restrict__ bsum, int nb, int* __restrict__ boff) {
    int t = threadIdx.x;  // 256 threads
    int v = (t < nb) ? bsum[t] : 0;
    __shared__ int sh[256];
    sh[t] = v;
    __syncthreads();
    for (int d = 1; d < 256; d <<= 1) {
        int u = (t >= d) ? sh[t - d] : 0;
        __syncthreads();
        sh[t] += u;
        __syncthreads();
    }
    if (t < nb) boff[t] = sh[t] - v;  // exclusive
}

__global__ void k_scan_final(const int* __restrict__ deg, int n, const int* __restrict__ boff,
                             int* __restrict__ offsets, int Etot) {
    int t = threadIdx.x;
    int base = blockIdx.x * 1024 + t * 4;
    int v[4];
    int s = 0;
#pragma unroll
    for (int j = 0; j < 4; j++) {
        int idx = base + j;
        v[j] = (idx < n) ? deg[idx] : 0;
        s += v[j];
    }
    __shared__ int sh[256];
    sh[t] = s;
    __syncthreads();
    for (int d = 1; d < 256; d <<= 1) {
        int u = (t >= d) ? sh[t - d] : 0;
        __syncthreads();
        sh[t] += u;
        __syncthreads();
    }
    int ex = sh[t] - s + boff[blockIdx.x];
#pragma unroll
    for (int j = 0; j < 4; j++) {
        int idx = base + j;
        if (idx < n) offsets[idx] = ex;
        ex += v[j];
    }
    if (blockIdx.x == 0 && t == 0) offsets[n] = Etot;
}

// scatter edges into dst-sorted order; one 8B payload: low=src|fake<<20, high=bf16 (vl,vh)
__global__ void k_scatter(const int* __restrict__ src, const int* __restrict__ dst,
                          const u16* __restrict__ avl, const u16* __restrict__ avh,
                          const int* __restrict__ lab, int E,
                          const int* __restrict__ offsets, int* __restrict__ cursor,
                          u64* __restrict__ epay, const int* __restrict__ flag) {
    int i = blockIdx.x * blockDim.x + threadIdx.x;
    if (i >= E) return;
    int isf32 = *flag;
    int d = dst[i];
    int pos = offsets[d] + atomicAdd(&cursor[d], 1);
    if ((unsigned)pos >= (unsigned)E) return;
    int s = src[i];
    int sl = lab[s], dl = lab[d];
    int fake = (sl < 0 || dl < 0) ? 2 : ((sl != dl) ? 1 : 0);
    u32 lo32 = (u32)(s | (fake << 20));
    u32 hi32 = isf32 ? packbf(((const float*)avl)[i], ((const float*)avh)[i])
                     : ((u32)avl[i] | ((u32)avh[i] << 16));
    epay[pos] = ((u64)hi32 << 32) | lo32;
}

// ---------------- phase A: x @ {W_low, W_high, W_mlp} ----------------

__launch_bounds__(256) __global__
void k_gemm(const u16* __restrict__ x, const u16* __restrict__ wl, const u16* __restrict__ wh,
            const u16* __restrict__ wm, int N, u32* __restrict__ xwlh, float* __restrict__ omlp,
            const int* __restrict__ flag) {
    int isf32 = *flag;
    __shared__ float WL[4096], WH[4096], WM[4096];
    for (int i = threadIdx.x; i < 4096; i += 256) {
        WL[i] = ldf(wl, i, isf32);
        WH[i] = ldf(wh, i, isf32);
        WM[i] = ldf(wm, i, isf32);
    }
    __syncthreads();
    int lane = threadIdx.x & 63;
    int wid = (blockIdx.x * 256 + threadIdx.x) >> 6;
    int nw = gridDim.x * 4;
    for (int r0 = wid * 8; r0 < N; r0 += nw * 8) {
        float xv[8];
#pragma unroll
        for (int j = 0; j < 8; j++) xv[j] = ldf(x, (r0 + j) * 64 + lane, isf32);
        float aL[8], aH[8], aM[8];
#pragma unroll
        for (int j = 0; j < 8; j++) { aL[j] = 0.f; aH[j] = 0.f; aM[j] = 0.f; }
        for (int k = 0; k < 64; k++) {
            float wlv = WL[k * 64 + lane];
            float whv = WH[k * 64 + lane];
            float wmv = WM[k * 64 + lane];
#pragma unroll
            for (int j = 0; j < 8; j++) {
                float xk = __shfl(xv[j], k, 64);
                aL[j] += xk * wlv;
                aH[j] += xk * whv;
                aM[j] += xk * wmv;
            }
        }
#pragma unroll
        for (int j = 0; j < 8; j++) {
            size_t o = (size_t)(r0 + j) * 64 + lane;
            xwlh[o] = packbf(sanitize(aL[j], 111.f), sanitize(aH[j], 111.f));
            omlp[o] = fmaxf(sanitize(aM[j], 111.f), 0.f);
        }
    }
}

// ---------------- phase B: spmm + relu ----------------
// 4 nodes per wave; 16-lane group owns one node's full 64-feature row
// (lane g=lane&15 holds feature dwords 4g..4g+3). Reduction-free.

__launch_bounds__(256) __global__
void k_spmm4n(const u32* __restrict__ xwlh, const u64* __restrict__ epay,
              const int* __restrict__ offsets, int N, int E, u32* __restrict__ outlh) {
    int lane = threadIdx.x & 63;
    int gwave = blockIdx.x * 4 + (threadIdx.x >> 6);
    int g = lane & 15, gi = lane >> 4;
    int node = gwave * 4 + gi;
    bool vn = node < N;
    int s = vn ? offsets[node] : 0;
    int e = vn ? offsets[node + 1] : 0;
    int deg = e - s;
    int md = deg;  // max degree across the 4 groups
    md = max(md, __shfl_xor(md, 16, 64));
    md = max(md, __shfl_xor(md, 32, 64));
    int Nm1 = N - 1, Em1 = E - 1;
    float aL[4] = {0.f, 0.f, 0.f, 0.f}, aH[4] = {0.f, 0.f, 0.f, 0.f};
    for (int t = 0; t < md; t += 2) {
#pragma unroll
        for (int u = 0; u < 2; u++) {
            int tt = t + u;
            int idx = min(max(s + min(tt, deg - 1), 0), Em1);
            u64 p = epay[idx];  // group-uniform address -> HW broadcast
            float w = (tt < deg) ? 1.f : 0.f;
            int sj = min((int)(p & 0xFFFFF), Nm1);
            u32 vv = (u32)(p >> 32);
            float vl = w * bflo(vv), vh = w * bfhi(vv);
            uint4 R = *((const uint4*)(xwlh + (size_t)sj * 64) + g);
            aL[0] += vl * bflo(R.x); aH[0] += vh * bfhi(R.x);
            aL[1] += vl * bflo(R.y); aH[1] += vh * bfhi(R.y);
            aL[2] += vl * bflo(R.z); aH[2] += vh * bfhi(R.z);
            aL[3] += vl * bflo(R.w); aH[3] += vh * bfhi(R.w);
        }
    }
    if (vn) {
        uint4 W;
        W.x = packbf(fmaxf(aL[0], 0.f), fmaxf(aH[0], 0.f));
        W.y = packbf(fmaxf(aL[1], 0.f), fmaxf(aH[1], 0.f));
        W.z = packbf(fmaxf(aL[2], 0.f), fmaxf(aH[2], 0.f));
        W.w = packbf(fmaxf(aL[3], 0.f), fmaxf(aH[3], 0.f));
        ((uint4*)(outlh + (size_t)node * 64))[g] = W;
    }
}

// ---------------- phase C+D fused: masked aggregation + attention ----------------
// same 4-nodes-per-wave layout; epilogue scalar chain serves 4 nodes at once

__launch_bounds__(256) __global__
void k_agg4n(const u32* __restrict__ outlh, const u64* __restrict__ epay,
             const int* __restrict__ offsets,
             const u16* __restrict__ aLF, const u16* __restrict__ aHF,
             const u16* __restrict__ aLB, const u16* __restrict__ aHB,
             const u16* __restrict__ aLU, const u16* __restrict__ aHU,
             const u16* __restrict__ aM, const u16* __restrict__ a7, int N, int E,
             float* __restrict__ out, const int* __restrict__ flag) {
    int isf32 = *flag;
    int lane = threadIdx.x & 63;
    int gwave = blockIdx.x * 4 + (threadIdx.x >> 6);
    int g = lane & 15, gi = lane >> 4;
    int node = gwave * 4 + gi;
    bool vn = node < N;
    int s = vn ? offsets[node] : 0;
    int e = vn ? offsets[node + 1] : 0;
    int deg = e - s;
    int md = deg;
    md = max(md, __shfl_xor(md, 16, 64));
    md = max(md, __shfl_xor(md, 32, 64));
    int Nm1 = N - 1, Em1 = E - 1;
    float heL[4] = {0, 0, 0, 0}, heH[4] = {0, 0, 0, 0};
    float hoL[4] = {0, 0, 0, 0}, hoH[4] = {0, 0, 0, 0};
    float unL[4] = {0, 0, 0, 0}, unH[4] = {0, 0, 0, 0};
    for (int t = 0; t < md; t += 2) {
#pragma unroll
        for (int u = 0; u < 2; u++) {
            int tt = t + u;
            int idx = min(max(s + min(tt, deg - 1), 0), Em1);
            u64 p = epay[idx];
            int fk = (int)(p >> 20) & 3;
            bool valid = (tt < deg);
            float whe = (valid && fk == 1) ? 1.f : 0.f;
            float who = (valid && fk == 0) ? 1.f : 0.f;
            float wun = (valid && fk == 2) ? 1.f : 0.f;
            int sj = min((int)(p & 0xFFFFF), Nm1);
            uint4 R = *((const uint4*)(outlh + (size_t)sj * 64) + g);
            float lo0 = bflo(R.x), hi0 = bfhi(R.x);
            float lo1 = bflo(R.y), hi1 = bfhi(R.y);
            float lo2 = bflo(R.z), hi2 = bfhi(R.z);
            float lo3 = bflo(R.w), hi3 = bfhi(R.w);
            heL[0] += whe * lo0; heH[0] += whe * hi0;
            heL[1] += whe * lo1; heH[1] += whe * hi1;
            heL[2] += whe * lo2; heH[2] += whe * hi2;
            heL[3] += whe * lo3; heH[3] += whe * hi3;
            hoL[0] += who * lo0; hoH[0] += who * hi0;
            hoL[1] += who * lo1; hoH[1] += who * hi1;
            hoL[2] += who * lo2; hoH[2] += who * hi2;
            hoL[3] += who * lo3; hoH[3] += who * hi3;
            unL[0] += wun * lo0; unH[0] += wun * hi0;
            unL[1] += wun * lo1; unH[1] += wun * hi1;
            unL[2] += wun * lo2; unH[2] += wun * hi2;
            unL[3] += wun * lo3; unH[3] += wun * hi3;
        }
    }
    // attention-vector slices for this lane's 4 features (same across groups)
    float vLF[4], vHF[4], vLB[4], vHB[4], vLU[4], vHU[4], vM[4];
    load4(aLF, g, isf32, vLF);
    load4(aHF, g, isf32, vHF);
    load4(aLB, g, isf32, vLB);
    load4(aHB, g, isf32, vHB);
    load4(aLU, g, isf32, vLU);
    load4(aHU, g, isf32, vHU);
    load4(aM, g, isf32, vM);
    float mvv[4] = {0.f, 0.f, 0.f, 0.f};
    if (vn) {
        float4 MV = ((const float4*)(out + (size_t)node * 64))[g];  // omlp staged in d_out
        mvv[0] = MV.x; mvv[1] = MV.y; mvv[2] = MV.z; mvv[3] = MV.w;
    }

    // 7 dot products; each group reduces over its own 16 lanes (full feature dim)
    float p0 = 0, p1 = 0, p2 = 0, p3 = 0, p4 = 0, p5 = 0, p6 = 0;
#pragma unroll
    for (int k = 0; k < 4; k++) {
        p0 += heL[k] * vLF[k];
        p1 += heH[k] * vHF[k];
        p2 += hoL[k] * vLB[k];
        p3 += hoH[k] * vHB[k];
        p4 += unL[k] * vLU[k];
        p5 += unH[k] * vHU[k];
        p6 += mvv[k] * vM[k];
    }
    float d0 = group_sum(p0), d1 = group_sum(p1), d2 = group_sum(p2), d3 = group_sum(p3);
    float d4 = group_sum(p4), d5 = group_sum(p5), d6 = group_sum(p6);

    float f[7];
    f[0] = 1.f / (1.f + expf(-d0));
    f[1] = 1.f / (1.f + expf(-d1));
    f[2] = 1.f / (1.f + expf(-d2));
    f[3] = 1.f / (1.f + expf(-d3));
    f[4] = 1.f / (1.f + expf(-d4));
    f[5] = 1.f / (1.f + expf(-d5));
    f[6] = 1.f / (1.f + expf(-d6));

    float z[7];
#pragma unroll
    for (int jj = 0; jj < 7; jj++) {
        float acc = 0.f;
#pragma unroll
        for (int i = 0; i < 7; i++) acc += f[i] * ldf(a7, i * 7 + jj, isf32);
        z[jj] = acc * (1.f / 7.f);
    }
    float m = z[0];
#pragma unroll
    for (int jj = 1; jj < 7; jj++) m = fmaxf(m, z[jj]);
    float wsum = 0.f;
    float wv[7];
#pragma unroll
    for (int jj = 0; jj < 7; jj++) { wv[jj] = expf(z[jj] - m); wsum += wv[jj]; }
    float s7 = 7.f / wsum;

    if (vn) {
        float4 W;
        float o0 = wv[0] * heL[0] + wv[1] * heH[0] + wv[2] * hoL[0] + wv[3] * hoH[0] +
                   wv[4] * unL[0] + wv[5] * unH[0] + wv[6] * mvv[0];
        float o1 = wv[0] * heL[1] + wv[1] * heH[1] + wv[2] * hoL[1] + wv[3] * hoH[1] +
                   wv[4] * unL[1] + wv[5] * unH[1] + wv[6] * mvv[1];
        float o2 = wv[0] * heL[2] + wv[1] * heH[2] + wv[2] * hoL[2] + wv[3] * hoH[2] +
                   wv[4] * unL[2] + wv[5] * unH[2] + wv[6] * mvv[2];
        float o3 = wv[0] * heL[3] + wv[1] * heH[3] + wv[2] * hoL[3] + wv[3] * hoH[3] +
                   wv[4] * unL[3] + wv[5] * unH[3] + wv[6] * mvv[3];
        W.x = sanitize(o0 * s7, 333.f);
        W.y = sanitize(o1 * s7, 333.f);
        W.z = sanitize(o2 * s7, 333.f);
        W.w = sanitize(o3 * s7, 333.f);
        ((float4*)(out + (size_t)node * 64))[g] = W;
    }
}

// ---------------- launcher ----------------

extern "C" void kernel_launch(void* const* d_in, const int* in_sizes, int n_in, void* d_out,
                              int out_size, void* d_ws, size_t ws_size, hipStream_t stream) {
    const u16* x = (const u16*)d_in[0];
    const u16* avl = (const u16*)d_in[1];
    const u16* avh = (const u16*)d_in[2];
    const u16* wl = (const u16*)d_in[3];
    const u16* wh = (const u16*)d_in[4];
    const u16* wm = (const u16*)d_in[5];
    const u16* aLF = (const u16*)d_in[6];
    const u16* aHF = (const u16*)d_in[7];
    const u16* aLB = (const u16*)d_in[8];
    const u16* aHB = (const u16*)d_in[9];
    const u16* aLU = (const u16*)d_in[10];
    const u16* aHU = (const u16*)d_in[11];
    const u16* aM = (const u16*)d_in[12];
    const u16* a7 = (const u16*)d_in[13];
    const int* esrc = (const int*)d_in[14];
    const int* edst = (const int*)d_in[15];
    const int* lab = (const int*)d_in[16];
    float* out = (float*)d_out;

    const int N = in_sizes[0] / 64;
    const int E = in_sizes[1];

    char* w = (char*)d_ws;
    size_t off = 0;
    auto alloc = [&](size_t bytes) -> char* {
        char* p = w + off;
        off += (bytes + 255) & ~(size_t)255;
        return p;
    };
    int* flag = (int*)alloc(256);
    int* offsets = (int*)alloc((size_t)(N + 1) * 4);
    int* degcur = (int*)alloc((size_t)2 * N * 4);
    int* bsum = (int*)alloc(256 * 4);
    int* boff = (int*)alloc(256 * 4);
    u64* epay = (u64*)alloc((size_t)E * 8);
    u32* xwlh = (u32*)alloc((size_t)N * 64 * 4);
    u32* outlh = (u32*)alloc((size_t)N * 64 * 4);

    if (ws_size < off) {
        k_sentinel<<<(out_size + 255) / 256, 256, 0, stream>>>(out, out_size, 1000.0f);
        return;
    }

    int* deg = degcur;
    int* cursor = degcur + N;
    int NB = (N + 1023) / 1024;  // must be <= 256

    k_zero_sniff<<<(2 * N + 255) / 256, 256, 0, stream>>>(degcur, 2 * N, x, flag);
    k_hist<<<(E + 255) / 256, 256, 0, stream>>>(edst, E, deg);
    k_scan_partial<<<NB, 256, 0, stream>>>(deg, N, bsum);
    k_scan_bsum<<<1, 256, 0, stream>>>(bsum, NB, boff);
    k_scan_final<<<NB, 256, 0, stream>>>(deg, N, boff, offsets, E);
    k_scatter<<<(E + 255) / 256, 256, 0, stream>>>(esrc, edst, avl, avh, lab, E, offsets, cursor,
                                                   epay, flag);

    k_gemm<<<512, 256, 0, stream>>>(x, wl, wh, wm, N, xwlh, out /* omlp in d_out */, flag);

    int nodeBlocks = (N + 15) / 16;  // 16 nodes per block (4 waves x 4 nodes)
    k_spmm4n<<<nodeBlocks, 256, 0, stream>>>(xwlh, epay, offsets, N, E, outlh);
    k_agg4n<<<nodeBlocks, 256, 0, stream>>>(outlh, epay, offsets, aLF, aHF, aLB, aHB, aLU, aHU,
                                            aM, a7, N, E, out, flag);
}

// Round 9
// 461.057 us; speedup vs baseline: 1.4901x; 1.1468x over previous
//
#include <hip/hip_runtime.h>
#include <hip/hip_bf16.h>

typedef unsigned int u32;
typedef unsigned short u16;
typedef unsigned long long u64;

typedef __attribute__((ext_vector_type(8))) short bf16x8;
typedef __attribute__((ext_vector_type(4))) float f32x4;

// bf16 = top 16 bits of fp32; RNE pack
static __device__ __forceinline__ float bflo(u32 u) { return __uint_as_float(u << 16); }
static __device__ __forceinline__ float bfhi(u32 u) { return __uint_as_float(u & 0xFFFF0000u); }
static __device__ __forceinline__ float bf2f(u16 u) { return __uint_as_float((u32)u << 16); }
static __device__ __forceinline__ u32 f2bf(float f) {
    u32 u = __float_as_uint(f);
    return (u + 0x7FFFu + ((u >> 16) & 1u)) >> 16;
}
static __device__ __forceinline__ u32 packbf(float lo, float hi) {
    return f2bf(lo) | (f2bf(hi) << 16);
}
static __device__ __forceinline__ float ldf(const u16* p16, int idx, int isf32) {
    return isf32 ? ((const float*)p16)[idx] : bf2f(p16[idx]);
}
// load 4 consecutive attention-vector elements [4*q .. 4*q+3]
static __device__ __forceinline__ void load4(const u16* p, int q, int isf32, float* v) {
    if (isf32) {
        float4 t = ((const float4*)p)[q];
        v[0] = t.x; v[1] = t.y; v[2] = t.z; v[3] = t.w;
    } else {
        u32 a = ((const u32*)p)[q * 2], b = ((const u32*)p)[q * 2 + 1];
        v[0] = bflo(a); v[1] = bfhi(a); v[2] = bflo(b); v[3] = bfhi(b);
    }
}
static __device__ __forceinline__ float sanitize(float v, float code) {
    return (fabsf(v) < 1e30f) ? v : code;
}

static __device__ __forceinline__ float wave_sum(float v) {
#pragma unroll
    for (int o = 32; o; o >>= 1) v += __shfl_xor(v, o, 64);
    return v;
}
// sum within 16-lane group (lanes grouped by lane>>4)
static __device__ __forceinline__ float group_sum(float v) {
#pragma unroll
    for (int o = 8; o; o >>= 1) v += __shfl_xor(v, o, 64);
    return v;
}

// ---------------- diagnostics / utility ----------------

__global__ void k_sentinel(float* __restrict__ out, int n, float val) {
    int i = blockIdx.x * blockDim.x + threadIdx.x;
    if (i < n) out[i] = val;
}

__global__ void k_zero_sniff(int* __restrict__ p, int n, const u16* __restrict__ x,
                             int* __restrict__ flag) {
    int i = blockIdx.x * blockDim.x + threadIdx.x;
    if (i < n) p[i] = 0;
    if (blockIdx.x == 0 && threadIdx.x < 64) {
        int lane = threadIdx.x;
        int wild = 0;
        for (int k = 0; k < 64; k++) {
            u32 u = x[lane * 64 + k];
            int e = (u >> 7) & 0xFF;
            if (e < 96 || e > 135) wild++;
        }
        float tot = wave_sum((float)wild);
        if (lane == 0) *flag = (tot > 200.f) ? 1 : 0;
    }
}

// ---------------- sort-by-dst machinery ----------------

__global__ void k_hist(const int* __restrict__ dst, int E, int* __restrict__ deg) {
    int i = blockIdx.x * blockDim.x + threadIdx.x;
    if (i < E) atomicAdd(&deg[dst[i]], 1);
}

__global__ void k_scan_partial(const int* __restrict__ deg, int n, int* __restrict__ bsum) {
    int t = threadIdx.x;
    int base = blockIdx.x * 1024 + t * 4;
    int s = 0;
#pragma unroll
    for (int j = 0; j < 4; j++) {
        int idx = base + j;
        if (idx < n) s += deg[idx];
    }
    __shared__ int sh[256];
    sh[t] = s;
    __syncthreads();
    for (int d = 128; d; d >>= 1) {
        if (t < d) sh[t] += sh[t + d];
        __syncthreads();
    }
    if (t == 0) bsum[blockIdx.x] = sh[0];
}

__global__ void k_scan_bsum(const int* __restrict__ bsum, int nb, int* __restrict__ boff) {
    int t = threadIdx.x;  // 256 threads
    int v = (t < nb) ? bsum[t] : 0;
    __shared__ int sh[256];
    sh[t] = v;
    __syncthreads();
    for (int d = 1; d < 256; d <<= 1) {
        int u = (t >= d) ? sh[t - d] : 0;
        __syncthreads();
        sh[t] += u;
        __syncthreads();
    }
    if (t < nb) boff[t] = sh[t] - v;  // exclusive
}

__global__ void k_scan_final(const int* __restrict__ deg, int n, const int* __restrict__ boff,
                             int* __restrict__ offsets, int Etot) {
    int t = threadIdx.x;
    int base = blockIdx.x * 1024 + t * 4;
    int v[4];
    int s = 0;
#pragma unroll
    for (int j = 0; j < 4; j++) {
        int idx = base + j;
        v[j] = (idx < n) ? deg[idx] : 0;
        s += v[j];
    }
    __shared__ int sh[256];
    sh[t] = s;
    __syncthreads();
    for (int d = 1; d < 256; d <<= 1) {
        int u = (t >= d) ? sh[t - d] : 0;
        __syncthreads();
        sh[t] += u;
        __syncthreads();
    }
    int ex = sh[t] - s + boff[blockIdx.x];
#pragma unroll
    for (int j = 0; j < 4; j++) {
        int idx = base + j;
        if (idx < n) offsets[idx] = ex;
        ex += v[j];
    }
    if (blockIdx.x == 0 && t == 0) offsets[n] = Etot;
}

// scatter edges into dst-sorted order; one 8B payload: low=src|fake<<20, high=bf16 (vl,vh)
__global__ void k_scatter(const int* __restrict__ src, const int* __restrict__ dst,
                          const u16* __restrict__ avl, const u16* __restrict__ avh,
                          const int* __restrict__ lab, int E,
                          const int* __restrict__ offsets, int* __restrict__ cursor,
                          u64* __restrict__ epay, const int* __restrict__ flag) {
    int i = blockIdx.x * blockDim.x + threadIdx.x;
    if (i >= E) return;
    int isf32 = *flag;
    int d = dst[i];
    int pos = offsets[d] + atomicAdd(&cursor[d], 1);
    if ((unsigned)pos >= (unsigned)E) return;
    int s = src[i];
    int sl = lab[s], dl = lab[d];
    int fake = (sl < 0 || dl < 0) ? 2 : ((sl != dl) ? 1 : 0);
    u32 lo32 = (u32)(s | (fake << 20));
    u32 hi32 = isf32 ? packbf(((const float*)avl)[i], ((const float*)avh)[i])
                     : ((u32)avl[i] | ((u32)avh[i] << 16));
    epay[pos] = ((u64)hi32 << 32) | lo32;
}

// ---------------- phase A: x @ {W_low, W_high, W_mlp} via MFMA ----------------
// Bpack[slot=ct*2+c][lane][j] : bf16 B-fragments, ct in [0,12) = 3 matrices x 4 col-tiles,
// c = K-chunk (k in [32c,32c+32)). Fragment: B[k=32c+quad*8+j][n=(ct&3)*16+(lane&15)].

__global__ void k_prepB(const u16* __restrict__ wl, const u16* __restrict__ wh,
                        const u16* __restrict__ wm, u16* __restrict__ Bpack,
                        const int* __restrict__ flag) {
    int isf32 = *flag;
    for (int idx = threadIdx.x; idx < 12 * 2 * 64; idx += 256) {
        int slot = idx >> 6;   // 0..23 = ct*2+c
        int ln = idx & 63;
        int ct = slot >> 1, c = slot & 1;
        int mat = ct >> 2;
        const u16* W = (mat == 0) ? wl : (mat == 1) ? wh : wm;
        int col = (ct & 3) * 16 + (ln & 15);
        int kbase = c * 32 + (ln >> 4) * 8;
        u16* dst = Bpack + (size_t)idx * 8;
#pragma unroll
        for (int j = 0; j < 8; j++) dst[j] = (u16)f2bf(ldf(W, (kbase + j) * 64 + col, isf32));
    }
}

// one wave per 16-row tile: 24 MFMAs compute rows x all 192 output cols
__launch_bounds__(256) __global__
void k_gemm_mfma(const u16* __restrict__ x, const u16* __restrict__ Bpack, int N,
                 u32* __restrict__ xwlh, float* __restrict__ omlp,
                 const int* __restrict__ flag) {
    int isf32 = *flag;
    int lane = threadIdx.x & 63;
    int wv = (blockIdx.x * 256 + threadIdx.x) >> 6;
    int nw = gridDim.x * 4;
    int m = lane & 15, quad = lane >> 4;
    int ntiles = (N + 15) >> 4;
    for (int tile = wv; tile < ntiles; tile += nw) {
        int r0 = tile * 16;
        int arow = min(r0 + m, N - 1);
        bf16x8 a[2];
#pragma unroll
        for (int c = 0; c < 2; c++) {
            int base = arow * 64 + c * 32 + quad * 8;
            if (isf32) {
                const float* xf = (const float*)x;
#pragma unroll
                for (int j = 0; j < 8; j++) a[c][j] = (short)f2bf(xf[base + j]);
            } else {
#pragma unroll
                for (int j = 0; j < 8; j++) a[c][j] = (short)x[base + j];
            }
        }
        f32x4 acc[12];
#pragma unroll
        for (int t = 0; t < 12; t++) acc[t] = (f32x4){0.f, 0.f, 0.f, 0.f};
#pragma unroll
        for (int t = 0; t < 12; t++) {
#pragma unroll
            for (int c = 0; c < 2; c++) {
                bf16x8 b = *(const bf16x8*)(Bpack + (size_t)((t * 2 + c) * 64 + lane) * 8);
                acc[t] = __builtin_amdgcn_mfma_f32_16x16x32_bf16(a[c], b, acc[t], 0, 0, 0);
            }
        }
        // C/D: col = lane&15, row = quad*4 + reg
#pragma unroll
        for (int t = 0; t < 4; t++) {
#pragma unroll
            for (int r = 0; r < 4; r++) {
                int row = r0 + quad * 4 + r;
                if (row < N) {
                    int o = row * 64 + t * 16 + m;
                    xwlh[o] = packbf(acc[t][r], acc[t + 4][r]);
                    omlp[o] = fmaxf(acc[t + 8][r], 0.f);
                }
            }
        }
    }
}

// ---------------- phase B: spmm + relu ----------------
// 4 nodes per wave; 16-lane group owns one node's full 64-feature row
// (lane g=lane&15 holds feature dwords 4g..4g+3). Reduction-free.

__launch_bounds__(256) __global__
void k_spmm4n(const u32* __restrict__ xwlh, const u64* __restrict__ epay,
              const int* __restrict__ offsets, int N, int E, u32* __restrict__ outlh) {
    int lane = threadIdx.x & 63;
    int gwave = blockIdx.x * 4 + (threadIdx.x >> 6);
    int g = lane & 15, gi = lane >> 4;
    int node = gwave * 4 + gi;
    bool vn = node < N;
    int s = vn ? offsets[node] : 0;
    int e = vn ? offsets[node + 1] : 0;
    int deg = e - s;
    int md = deg;  // max degree across the 4 groups
    md = max(md, __shfl_xor(md, 16, 64));
    md = max(md, __shfl_xor(md, 32, 64));
    int Nm1 = N - 1, Em1 = E - 1;
    float aL[4] = {0.f, 0.f, 0.f, 0.f}, aH[4] = {0.f, 0.f, 0.f, 0.f};
    for (int t = 0; t < md; t += 2) {
#pragma unroll
        for (int u = 0; u < 2; u++) {
            int tt = t + u;
            int idx = min(max(s + min(tt, deg - 1), 0), Em1);
            u64 p = epay[idx];  // group-uniform address -> HW broadcast
            float w = (tt < deg) ? 1.f : 0.f;
            int sj = min((int)(p & 0xFFFFF), Nm1);
            u32 vv = (u32)(p >> 32);
            float vl = w * bflo(vv), vh = w * bfhi(vv);
            uint4 R = *((const uint4*)(xwlh + (size_t)sj * 64) + g);
            aL[0] += vl * bflo(R.x); aH[0] += vh * bfhi(R.x);
            aL[1] += vl * bflo(R.y); aH[1] += vh * bfhi(R.y);
            aL[2] += vl * bflo(R.z); aH[2] += vh * bfhi(R.z);
            aL[3] += vl * bflo(R.w); aH[3] += vh * bfhi(R.w);
        }
    }
    if (vn) {
        uint4 W;
        W.x = packbf(fmaxf(aL[0], 0.f), fmaxf(aH[0], 0.f));
        W.y = packbf(fmaxf(aL[1], 0.f), fmaxf(aH[1], 0.f));
        W.z = packbf(fmaxf(aL[2], 0.f), fmaxf(aH[2], 0.f));
        W.w = packbf(fmaxf(aL[3], 0.f), fmaxf(aH[3], 0.f));
        ((uint4*)(outlh + (size_t)node * 64))[g] = W;
    }
}

// ---------------- phase C+D fused: masked aggregation + attention ----------------
// same 4-nodes-per-wave layout; epilogue scalar chain serves 4 nodes at once

__launch_bounds__(256) __global__
void k_agg4n(const u32* __restrict__ outlh, const u64* __restrict__ epay,
             const int* __restrict__ offsets,
             const u16* __restrict__ aLF, const u16* __restrict__ aHF,
             const u16* __restrict__ aLB, const u16* __restrict__ aHB,
             const u16* __restrict__ aLU, const u16* __restrict__ aHU,
             const u16* __restrict__ aM, const u16* __restrict__ a7, int N, int E,
             float* __restrict__ out, const int* __restrict__ flag) {
    int isf32 = *flag;
    int lane = threadIdx.x & 63;
    int gwave = blockIdx.x * 4 + (threadIdx.x >> 6);
    int g = lane & 15, gi = lane >> 4;
    int node = gwave * 4 + gi;
    bool vn = node < N;
    int s = vn ? offsets[node] : 0;
    int e = vn ? offsets[node + 1] : 0;
    int deg = e - s;
    int md = deg;
    md = max(md, __shfl_xor(md, 16, 64));
    md = max(md, __shfl_xor(md, 32, 64));
    int Nm1 = N - 1, Em1 = E - 1;
    float heL[4] = {0, 0, 0, 0}, heH[4] = {0, 0, 0, 0};
    float hoL[4] = {0, 0, 0, 0}, hoH[4] = {0, 0, 0, 0};
    float unL[4] = {0, 0, 0, 0}, unH[4] = {0, 0, 0, 0};
    for (int t = 0; t < md; t += 2) {
#pragma unroll
        for (int u = 0; u < 2; u++) {
            int tt = t + u;
            int idx = min(max(s + min(tt, deg - 1), 0), Em1);
            u64 p = epay[idx];
            int fk = (int)(p >> 20) & 3;
            bool valid = (tt < deg);
            float whe = (valid && fk == 1) ? 1.f : 0.f;
            float who = (valid && fk == 0) ? 1.f : 0.f;
            float wun = (valid && fk == 2) ? 1.f : 0.f;
            int sj = min((int)(p & 0xFFFFF), Nm1);
            uint4 R = *((const uint4*)(outlh + (size_t)sj * 64) + g);
            float lo0 = bflo(R.x), hi0 = bfhi(R.x);
            float lo1 = bflo(R.y), hi1 = bfhi(R.y);
            float lo2 = bflo(R.z), hi2 = bfhi(R.z);
            float lo3 = bflo(R.w), hi3 = bfhi(R.w);
            heL[0] += whe * lo0; heH[0] += whe * hi0;
            heL[1] += whe * lo1; heH[1] += whe * hi1;
            heL[2] += whe * lo2; heH[2] += whe * hi2;
            heL[3] += whe * lo3; heH[3] += whe * hi3;
            hoL[0] += who * lo0; hoH[0] += who * hi0;
            hoL[1] += who * lo1; hoH[1] += who * hi1;
            hoL[2] += who * lo2; hoH[2] += who * hi2;
            hoL[3] += who * lo3; hoH[3] += who * hi3;
            unL[0] += wun * lo0; unH[0] += wun * hi0;
            unL[1] += wun * lo1; unH[1] += wun * hi1;
            unL[2] += wun * lo2; unH[2] += wun * hi2;
            unL[3] += wun * lo3; unH[3] += wun * hi3;
        }
    }
    // attention-vector slices for this lane's 4 features (same across groups)
    float vLF[4], vHF[4], vLB[4], vHB[4], vLU[4], vHU[4], vM[4];
    load4(aLF, g, isf32, vLF);
    load4(aHF, g, isf32, vHF);
    load4(aLB, g, isf32, vLB);
    load4(aHB, g, isf32, vHB);
    load4(aLU, g, isf32, vLU);
    load4(aHU, g, isf32, vHU);
    load4(aM, g, isf32, vM);
    float mvv[4] = {0.f, 0.f, 0.f, 0.f};
    if (vn) {
        float4 MV = ((const float4*)(out + (size_t)node * 64))[g];  // omlp staged in d_out
        mvv[0] = MV.x; mvv[1] = MV.y; mvv[2] = MV.z; mvv[3] = MV.w;
    }

    // 7 dot products; each group reduces over its own 16 lanes (full feature dim)
    float p0 = 0, p1 = 0, p2 = 0, p3 = 0, p4 = 0, p5 = 0, p6 = 0;
#pragma unroll
    for (int k = 0; k < 4; k++) {
        p0 += heL[k] * vLF[k];
        p1 += heH[k] * vHF[k];
        p2 += hoL[k] * vLB[k];
        p3 += hoH[k] * vHB[k];
        p4 += unL[k] * vLU[k];
        p5 += unH[k] * vHU[k];
        p6 += mvv[k] * vM[k];
    }
    float d0 = group_sum(p0), d1 = group_sum(p1), d2 = group_sum(p2), d3 = group_sum(p3);
    float d4 = group_sum(p4), d5 = group_sum(p5), d6 = group_sum(p6);

    float f[7];
    f[0] = 1.f / (1.f + expf(-d0));
    f[1] = 1.f / (1.f + expf(-d1));
    f[2] = 1.f / (1.f + expf(-d2));
    f[3] = 1.f / (1.f + expf(-d3));
    f[4] = 1.f / (1.f + expf(-d4));
    f[5] = 1.f / (1.f + expf(-d5));
    f[6] = 1.f / (1.f + expf(-d6));

    float z[7];
#pragma unroll
    for (int jj = 0; jj < 7; jj++) {
        float acc = 0.f;
#pragma unroll
        for (int i = 0; i < 7; i++) acc += f[i] * ldf(a7, i * 7 + jj, isf32);
        z[jj] = acc * (1.f / 7.f);
    }
    float m = z[0];
#pragma unroll
    for (int jj = 1; jj < 7; jj++) m = fmaxf(m, z[jj]);
    float wsum = 0.f;
    float wv[7];
#pragma unroll
    for (int jj = 0; jj < 7; jj++) { wv[jj] = expf(z[jj] - m); wsum += wv[jj]; }
    float s7 = 7.f / wsum;

    if (vn) {
        float4 W;
        float o0 = wv[0] * heL[0] + wv[1] * heH[0] + wv[2] * hoL[0] + wv[3] * hoH[0] +
                   wv[4] * unL[0] + wv[5] * unH[0] + wv[6] * mvv[0];
        float o1 = wv[0] * heL[1] + wv[1] * heH[1] + wv[2] * hoL[1] + wv[3] * hoH[1] +
                   wv[4] * unL[1] + wv[5] * unH[1] + wv[6] * mvv[1];
        float o2 = wv[0] * heL[2] + wv[1] * heH[2] + wv[2] * hoL[2] + wv[3] * hoH[2] +
                   wv[4] * unL[2] + wv[5] * unH[2] + wv[6] * mvv[2];
        float o3 = wv[0] * heL[3] + wv[1] * heH[3] + wv[2] * hoL[3] + wv[3] * hoH[3] +
                   wv[4] * unL[3] + wv[5] * unH[3] + wv[6] * mvv[3];
        W.x = sanitize(o0 * s7, 333.f);
        W.y = sanitize(o1 * s7, 333.f);
        W.z = sanitize(o2 * s7, 333.f);
        W.w = sanitize(o3 * s7, 333.f);
        ((float4*)(out + (size_t)node * 64))[g] = W;
    }
}

// ---------------- launcher ----------------

extern "C" void kernel_launch(void* const* d_in, const int* in_sizes, int n_in, void* d_out,
                              int out_size, void* d_ws, size_t ws_size, hipStream_t stream) {
    const u16* x = (const u16*)d_in[0];
    const u16* avl = (const u16*)d_in[1];
    const u16* avh = (const u16*)d_in[2];
    const u16* wl = (const u16*)d_in[3];
    const u16* wh = (const u16*)d_in[4];
    const u16* wm = (const u16*)d_in[5];
    const u16* aLF = (const u16*)d_in[6];
    const u16* aHF = (const u16*)d_in[7];
    const u16* aLB = (const u16*)d_in[8];
    const u16* aHB = (const u16*)d_in[9];
    const u16* aLU = (const u16*)d_in[10];
    const u16* aHU = (const u16*)d_in[11];
    const u16* aM = (const u16*)d_in[12];
    const u16* a7 = (const u16*)d_in[13];
    const int* esrc = (const int*)d_in[14];
    const int* edst = (const int*)d_in[15];
    const int* lab = (const int*)d_in[16];
    float* out = (float*)d_out;

    const int N = in_sizes[0] / 64;
    const int E = in_sizes[1];

    char* w = (char*)d_ws;
    size_t off = 0;
    auto alloc = [&](size_t bytes) -> char* {
        char* p = w + off;
        off += (bytes + 255) & ~(size_t)255;
        return p;
    };
    int* flag = (int*)alloc(256);
    int* offsets = (int*)alloc((size_t)(N + 1) * 4);
    int* degcur = (int*)alloc((size_t)2 * N * 4);
    int* bsum = (int*)alloc(256 * 4);
    int* boff = (int*)alloc(256 * 4);
    u16* Bpack = (u16*)alloc(12 * 2 * 64 * 8 * 2);  // 24 KB fragment-ordered weights
    u64* epay = (u64*)alloc((size_t)E * 8);
    u32* xwlh = (u32*)alloc((size_t)N * 64 * 4);
    u32* outlh = (u32*)alloc((size_t)N * 64 * 4);

    if (ws_size < off) {
        k_sentinel<<<(out_size + 255) / 256, 256, 0, stream>>>(out, out_size, 1000.0f);
        return;
    }

    int* deg = degcur;
    int* cursor = degcur + N;
    int NB = (N + 1023) / 1024;  // must be <= 256

    k_zero_sniff<<<(2 * N + 255) / 256, 256, 0, stream>>>(degcur, 2 * N, x, flag);
    k_hist<<<(E + 255) / 256, 256, 0, stream>>>(edst, E, deg);
    k_scan_partial<<<NB, 256, 0, stream>>>(deg, N, bsum);
    k_scan_bsum<<<1, 256, 0, stream>>>(bsum, NB, boff);
    k_scan_final<<<NB, 256, 0, stream>>>(deg, N, boff, offsets, E);
    k_scatter<<<(E + 255) / 256, 256, 0, stream>>>(esrc, edst, avl, avh, lab, E, offsets, cursor,
                                                   epay, flag);

    k_prepB<<<1, 256, 0, stream>>>(wl, wh, wm, Bpack, flag);
    int ntiles = (N + 15) / 16;                 // one 16-row tile per wave
    int gemmBlocks = (ntiles + 3) / 4;
    k_gemm_mfma<<<gemmBlocks, 256, 0, stream>>>(x, Bpack, N, xwlh, out /* omlp in d_out */, flag);

    int nodeBlocks = (N + 15) / 16;  // 16 nodes per block (4 waves x 4 nodes)
    k_spmm4n<<<nodeBlocks, 256, 0, stream>>>(xwlh, epay, offsets, N, E, outlh);
    k_agg4n<<<nodeBlocks, 256, 0, stream>>>(outlh, epay, offsets, aLF, aHF, aLB, aHB, aLU, aHU,
                                            aM, a7, N, E, out, flag);
}